// Round 10
// baseline (234.274 us; speedup 1.0000x reference)
//
#include <hip/hip_runtime.h>

#define NN 40000
#define SS 16
#define CC 96
#define GG 12
#define CP 100
#define SXP 104   // ushort stride for qkv transpose buffer: 208 B rows, 16B-aligned frag reads

typedef __attribute__((ext_vector_type(8))) short bf16x8;
typedef __attribute__((ext_vector_type(4))) float f32x4;

// float -> bf16 (RNE), raw 16-bit pattern (prep-path quality)
__device__ __forceinline__ short f2bf(float f) {
    union { float f; unsigned u; } c; c.f = f;
    unsigned r = (c.u + 0x7fffu + ((c.u >> 16) & 1u)) >> 16;
    return (short)r;
}
// pack two floats -> (bf16(hi)<<16)|bf16(lo) in ONE v_perm_b32 (+half-up rounding)
__device__ __forceinline__ unsigned pack2bf(float hi, float lo) {
    unsigned a = __float_as_uint(hi) + 0x8000u;
    unsigned b = __float_as_uint(lo) + 0x8000u;
    return __builtin_amdgcn_perm(a, b, 0x07060302u);
}
// single float -> bf16 (half-up, 2 ops)
__device__ __forceinline__ ushort f2bf_hu(float f) {
    return (ushort)((__float_as_uint(f) + 0x8000u) >> 16);
}

// ---- DPP cross-lane within 16-lane rows (~2 cyc vs ~120 for ds_bpermute) ----
template<int CTRL>
__device__ __forceinline__ float dppf(float x) {
    int r = __builtin_amdgcn_mov_dpp(__float_as_int(x), CTRL, 0xF, 0xF, true);
    return __int_as_float(r);
}
__device__ __forceinline__ float row16_sum(float x) {
    x += dppf<0xB1>(x);    // quad_perm [1,0,3,2]
    x += dppf<0x4E>(x);    // quad_perm [2,3,0,1]
    x += dppf<0x141>(x);   // ROW_HALF_MIRROR
    x += dppf<0x140>(x);   // ROW_MIRROR
    return x;
}
__device__ __forceinline__ float row16_max(float x) {
    x = fmaxf(x, dppf<0xB1>(x));
    x = fmaxf(x, dppf<0x4E>(x));
    x = fmaxf(x, dppf<0x141>(x));
    x = fmaxf(x, dppf<0x140>(x));
    return x;
}

// job-range constants for prep
#define J_W3   27648            // 3 x 9216: Wq/Wk/Wv frags
#define J_P2   (J_W3 + 9216)    // Wp2 frags
#define J_W1   (J_P2 + 1536)    // Ww1 frags (padded to 16 cols)
#define J_WF   (J_W1 + 1536)    // Wfused frags (direct 96-dot)
#define J_CF   (J_WF + 12)      // cfused
#define J_S4   (J_CF + 4)       // s4 = A^T 1
#define J_G    (J_S4 + 16)      // G = A^T A
// grid = ceil(J_G/256) = 157

// ---------------- prep: all weight fragments + LN-stats, once ----------------
__global__ void prep_kernel(const float* __restrict__ Wq, const float* __restrict__ Wk,
                            const float* __restrict__ Wv, const float* __restrict__ Wp2,
                            const float* __restrict__ Ww1, const float* __restrict__ bp2,
                            const float* __restrict__ bw1, const float* __restrict__ Wp1,
                            const float* __restrict__ bp1,
                            ushort* __restrict__ fragQKV, ushort* __restrict__ fragP2,
                            ushort* __restrict__ fragW1, ushort* __restrict__ fragWf,
                            float* __restrict__ cfused, float* __restrict__ stats)
{
    const int job = blockIdx.x*256 + threadIdx.x;
    if (job < J_W3) {
        const int which = job / 9216, o = job % 9216;
        const float* W = (which == 0) ? Wq : (which == 1) ? Wk : Wv;
        const int pos = o >> 3, j = o & 7;
        const int lane = pos & 63, ntkb = pos >> 6;
        const int nt = ntkb / 3, kb = ntkb - nt*3;
        const int col = nt*16 + (lane & 15), krow = kb*32 + (lane >> 4)*8 + j;
        fragQKV[job] = (ushort)f2bf(W[krow*CC + col]);
    } else if (job < J_P2) {
        const int o = job - J_W3;
        const int pos = o >> 3, j = o & 7;
        const int lane = pos & 63, ntkb = pos >> 6;
        const int nt = ntkb / 3, kb = ntkb - nt*3;
        const int col = nt*16 + (lane & 15), krow = kb*32 + (lane >> 4)*8 + j;
        fragP2[o] = (ushort)f2bf(Wp2[krow*CC + col]);
    } else if (job < J_W1) {
        const int o = job - J_P2;
        const int pos = o >> 3, j = o & 7;
        const int lane = pos & 63, kb = pos >> 6;
        const int col = lane & 15, krow = kb*32 + (lane >> 4)*8 + j;
        fragW1[o] = (col < GG) ? (ushort)f2bf(Ww1[krow*GG + col]) : (ushort)0;
    } else if (job < J_WF) {
        const int o = job - J_W1;
        const int pos = o >> 3, j = o & 7;
        const int lane = pos & 63, kb = pos >> 6;
        const int col = lane & 15, krow = kb*32 + (lane >> 4)*8 + j;
        float s = 0.f;
        if (col < GG) for (int jj = 0; jj < CC; ++jj) s += Wp2[krow*CC + jj] * Ww1[jj*GG + col];
        fragWf[o] = (col < GG) ? (ushort)f2bf(s) : (ushort)0;
    } else if (job < J_CF) {
        const int g = job - J_WF;
        float s = bw1[g];
        for (int jj = 0; jj < CC; ++jj) s += bp2[jj] * Ww1[jj*GG + g];
        cfused[g] = s;
    } else if (job < J_S4) {
        const int d = job - J_CF;
        float s = 0.f;
        for (int c = 0; c < CC; ++c) s += (d < 3) ? Wp1[d*CC + c] : bp1[c];
        stats[d] = s;
    } else if (job < J_G) {
        const int o = job - J_S4, d1 = o >> 2, d2 = o & 3;
        float s = 0.f;
        for (int c = 0; c < CC; ++c) {
            const float a1 = (d1 < 3) ? Wp1[d1*CC + c] : bp1[c];
            const float a2 = (d2 < 3) ? Wp1[d2*CC + c] : bp1[c];
            s += a1*a2;
        }
        stats[4 + o] = s;
    }
}

// ---------------- Kernel A: q/k/v projections via MFMA, ONE tile per wave ----------------
// B-frags read straight from global (L2-resident, coalesced 1 KB/wave per frag) —
// no 18 KB LDS staging. Transpose buffer is bf16 (stride 104 ush: 16B-aligned reads,
// 2-way bank aliasing = free). LDS ~14.5 KB.
__global__ __launch_bounds__(256) void qkv_mfma(
    const float* __restrict__ q, const float* __restrict__ kx, const float* __restrict__ v,
    const float* __restrict__ bq, const float* __restrict__ gq, const float* __restrict__ betaq,
    const float* __restrict__ bk, const float* __restrict__ gk, const float* __restrict__ betak,
    const float* __restrict__ bv,
    const ushort* __restrict__ fragQKV, const ushort* __restrict__ fragW1,
    float* __restrict__ valout, float* __restrict__ qw1out, float* __restrict__ kw1out)
{
    __shared__ float sbias[CC], sg[CC], sbeta[CC];
    __shared__ __align__(16) ushort sx2[4][16*SXP];   // per-wave bf16 transpose buffer

    const int p = blockIdx.y;
    const float* X; const float* b;
    const float* g = nullptr; const float* beta = nullptr;
    if (p == 0)      { X = q;  b = bq; g = gq; beta = betaq; }
    else if (p == 1) { X = kx; b = bk; g = gk; beta = betak; }
    else             { X = v;  b = bv; }
    const bool has_ln = (p < 2);
    float* w1out = (p == 0) ? qw1out : kw1out;

    const int t = threadIdx.x;
    if (t < CC) {
        sbias[t] = b[t];
        if (has_ln) { sg[t] = g[t]; sbeta[t] = beta[t]; }
    }

    const int lane = t & 63, w = t >> 6;
    const int c16 = lane & 15, quad = lane >> 4;
    const ushort* fragW = fragQKV + p*9216;

    bf16x8 Ww1f[3];
    if (has_ln) {
        #pragma unroll
        for (int kb = 0; kb < 3; ++kb) {
            union { bf16x8 v; uint4 u; } wu;
            wu.u = ((const uint4*)fragW1)[kb*64 + lane];
            Ww1f[kb] = wu.v;
        }
    }

    __syncthreads();

    const f32x4 zero4 = {0.f, 0.f, 0.f, 0.f};
    ushort* sxw = sx2[w];
    const int tile = blockIdx.x*4 + w;     // exactly 2500 tiles
    const int row0 = tile * 16;

    const float* xr = X + (size_t)(row0 + c16)*CC;
    bf16x8 Af[3];
    #pragma unroll
    for (int kb = 0; kb < 3; ++kb) {
        const float4 a0 = *(const float4*)(xr + kb*32 + quad*8);
        const float4 a1 = *(const float4*)(xr + kb*32 + quad*8 + 4);
        union { bf16x8 v; uint u[4]; } au;
        au.u[0] = pack2bf(a0.y, a0.x);
        au.u[1] = pack2bf(a0.w, a0.z);
        au.u[2] = pack2bf(a1.y, a1.x);
        au.u[3] = pack2bf(a1.w, a1.z);
        Af[kb] = au.v;
    }

    f32x4 acc[6];
    #pragma unroll
    for (int nt = 0; nt < 6; ++nt) acc[nt] = zero4;
    #pragma unroll
    for (int kb = 0; kb < 3; ++kb)
        #pragma unroll
        for (int nt = 0; nt < 6; ++nt) {
            const bf16x8 bf = *(const bf16x8*)(fragW + ((nt*3 + kb)*64 + lane)*8);
            acc[nt] = __builtin_amdgcn_mfma_f32_16x16x32_bf16(Af[kb], bf, acc[nt], 0, 0, 0);
        }

    #pragma unroll
    for (int nt = 0; nt < 6; ++nt) {
        const float bb = sbias[nt*16 + c16];
        #pragma unroll
        for (int r = 0; r < 4; ++r) acc[nt][r] += bb;
    }

    if (has_ln) {
        #pragma unroll
        for (int r = 0; r < 4; ++r) {
            float sum = 0.f, sq = 0.f;
            #pragma unroll
            for (int nt = 0; nt < 6; ++nt) { float x = acc[nt][r]; sum += x; sq += x*x; }
            sum = row16_sum(sum); sq = row16_sum(sq);
            const float mu  = sum * (1.f/96.f);
            const float var = sq * (1.f/96.f) - mu*mu;
            const float rs  = rsqrtf(var + 1e-5f);
            #pragma unroll
            for (int nt = 0; nt < 6; ++nt) {
                const int c = nt*16 + c16;
                acc[nt][r] = fmaxf((acc[nt][r] - mu)*rs*sg[c] + sbeta[c], 0.f);
            }
        }
        // C/D -> per-wave bf16 LDS -> direct A-frag readback (no repacking)
        #pragma unroll
        for (int nt = 0; nt < 6; ++nt)
            #pragma unroll
            for (int r = 0; r < 4; ++r)
                sxw[(quad*4 + r)*SXP + nt*16 + c16] = f2bf_hu(acc[nt][r]);

        f32x4 o = zero4;
        #pragma unroll
        for (int kb = 0; kb < 3; ++kb) {
            const bf16x8 aA = *(const bf16x8*)(sxw + c16*SXP + kb*32 + quad*8);
            o = __builtin_amdgcn_mfma_f32_16x16x32_bf16(aA, Ww1f[kb], o, 0, 0, 0);
        }
        if (c16 < GG) {
            #pragma unroll
            for (int r = 0; r < 4; ++r)
                w1out[(size_t)(row0 + quad*4 + r)*GG + c16] = o[r];
        }
    } else {
        #pragma unroll
        for (int r = 0; r < 4; ++r)
            #pragma unroll
            for (int nt = 0; nt < 6; ++nt)
                valout[(size_t)(row0 + quad*4 + r)*CC + nt*16 + c16] = acc[nt][r];
    }
}

// ---------------- Kernel B: grouped vector attention, ONE node per wave ----------------
// grid 10000. B-frags read straight from global (L2-resident); Wfused frags in 12
// VGPRs; yb/sw share one LDS buffer (wave-synchronous: all yb reads precede sw
// writes). LDS ~7 KB -> occupancy caps at waves, not LDS. NEVER force min-occupancy
// (R4/R6 spills).
__global__ __launch_bounds__(256) void attn2(
    const float* __restrict__ xyz, const int* __restrict__ refidx,
    const float* __restrict__ gp,  const float* __restrict__ betap,
    const float* __restrict__ Wp1, const float* __restrict__ bp1,
    const float* __restrict__ bp2,
    const float* __restrict__ gw,  const float* __restrict__ betaw,
    const float* __restrict__ Ww2, const float* __restrict__ bw2,
    const float* __restrict__ cfused, const float* __restrict__ stats,
    const ushort* __restrict__ fragP2, const ushort* __restrict__ fragWf,
    const float* __restrict__ valw, const float* __restrict__ kw1w, const float* __restrict__ qw1w,
    float* __restrict__ out)
{
    __shared__ float4 sA[CC];                      // (Wp1 row0, row1, row2, bp1) per col
    __shared__ float2 sGB[CC];                     // (gp, betap) per col
    __shared__ float  sbp2[CC];
    __shared__ float  sWw2[GG*GG];
    __shared__ float  sgw[16], sbetaw[16], sbw2[16], scf[16];
    __shared__ float  sstats[20];
    __shared__ float  ybuf[4][SS*GG];              // yb then sw (aliased, wave-local)

    const int t = threadIdx.x;
    if (t < CC) {
        sA[t]  = make_float4(Wp1[t], Wp1[CC + t], Wp1[2*CC + t], bp1[t]);
        sGB[t] = make_float2(gp[t], betap[t]);
        sbp2[t] = bp2[t];
    }
    if (t < GG*GG) sWw2[t] = Ww2[t];
    if (t < 16) {
        sgw[t]    = (t < GG) ? gw[t]     : 0.f;
        sbetaw[t] = (t < GG) ? betaw[t]  : 0.f;
        sbw2[t]   = (t < GG) ? bw2[t]    : 0.f;
        scf[t]    = (t < GG) ? cfused[t] : 0.f;
    }
    if (t < 20) sstats[t] = stats[t];

    const int lane = t & 63, w = t >> 6;
    const int c16 = lane & 15, quad = lane >> 4;
    const int gcl = (c16 < GG) ? c16 : (GG-1);

    // Wfused B-frags in registers (one-time coalesced load)
    bf16x8 Wff[3];
    #pragma unroll
    for (int kb = 0; kb < 3; ++kb) {
        union { bf16x8 v; uint4 u; } wu;
        wu.u = ((const uint4*)fragWf)[kb*64 + lane];
        Wff[kb] = wu.v;
    }

    __syncthreads();   // param staging done; below is wave-synchronous

    float* yb = ybuf[w];
    float* sw = ybuf[w];   // aliased: all yb reads complete before sw writes
    const f32x4 zero4 = {0.f, 0.f, 0.f, 0.f};

    const int n = blockIdx.x*4 + w;   // one node per wave

    // ---- per-lane neighbor (s = c16) for t1 ----
    const int   id   = refidx[(size_t)n*SS + c16];
    const float m    = (id >= 0) ? 1.f : 0.f;
    const int   safe = (id < 0) ? 0 : id;

    // ---- C/D-layout row indices (s = quad*4+r), loaded EARLY so the kw1
    // gather latency overlaps t1 compute
    int sid[4]; float mr[4], kwv[4];
    #pragma unroll
    for (int r = 0; r < 4; ++r) {
        const int sd = refidx[(size_t)n*SS + quad*4 + r];
        mr[r]  = (sd >= 0) ? 1.f : 0.f;
        sid[r] = (sd < 0) ? 0 : sd;
    }
    #pragma unroll
    for (int r = 0; r < 4; ++r)
        kwv[r] = kw1w[(size_t)sid[r]*GG + gcl] * mr[r];
    const float qv = qw1w[(size_t)n*GG + gcl];

    const float px = (xyz[(size_t)safe*3 + 0] - xyz[(size_t)n*3 + 0]) * m;
    const float py = (xyz[(size_t)safe*3 + 1] - xyz[(size_t)n*3 + 1]) * m;
    const float pz = (xyz[(size_t)safe*3 + 2] - xyz[(size_t)n*3 + 2]) * m;

    // ---- LN stats of (pos@Wp1+bp1) from precomputed s4/G: no reduction ----
    const float mu = (px*sstats[0] + py*sstats[1] + pz*sstats[2] + sstats[3]) * (1.f/96.f);
    float e2 = 0.f;
    {
        const float p4[4] = {px, py, pz, 1.f};
        #pragma unroll
        for (int a = 0; a < 4; ++a) {
            float ta = 0.f;
            #pragma unroll
            for (int b2 = 0; b2 < 4; ++b2) ta = fmaf(sstats[4 + a*4 + b2], p4[b2], ta);
            e2 = fmaf(p4[a], ta, e2);
        }
    }
    const float var = e2*(1.f/96.f) - mu*mu;
    const float rs  = rsqrtf(var + 1e-5f);

    // ---- t1 = relu(ln(..)) directly into A-frag bf16 (perm-packed) ----
    bf16x8 t1A[3];
    #pragma unroll
    for (int kb = 0; kb < 3; ++kb) {
        union { bf16x8 v; uint u[4]; } tu;
        #pragma unroll
        for (int jp = 0; jp < 4; ++jp) {
            float tt[2];
            #pragma unroll
            for (int h = 0; h < 2; ++h) {
                const int c = kb*32 + quad*8 + jp*2 + h;
                const float4 aw = sA[c];
                const float x = fmaf(px, aw.x, fmaf(py, aw.y, fmaf(pz, aw.z, aw.w)));
                const float2 gb = sGB[c];
                tt[h] = fmaxf(fmaf((x - mu)*rs, gb.x, gb.y), 0.f);
            }
            tu.u[jp] = pack2bf(tt[1], tt[0]);
        }
        t1A[kb] = tu.v;
    }

    // ---- t2 = t1 @ Wfused (frags in regs) ----
    f32x4 t2 = zero4;
    #pragma unroll
    for (int kb = 0; kb < 3; ++kb)
        t2 = __builtin_amdgcn_mfma_f32_16x16x32_bf16(t1A[kb], Wff[kb], t2, 0, 0, 0);
    #pragma unroll
    for (int r = 0; r < 4; ++r)
        t2[r] += kwv[r] - qv + scf[c16];

    // LN over G=12 (rows s=quad*4+r, lane col g=c16) via DPP
    #pragma unroll
    for (int r = 0; r < 4; ++r) {
        const float x = (c16 < GG) ? t2[r] : 0.f;
        const float s1 = row16_sum(x);
        const float s2 = row16_sum(x*x);
        const float mu2  = s1 * (1.f/12.f);
        const float var2 = s2 * (1.f/12.f) - mu2*mu2;
        const float rs2  = rsqrtf(var2 + 1e-5f);
        const float y    = fmaxf((t2[r] - mu2)*rs2*sgw[c16] + sbetaw[c16], 0.f);
        if (c16 < GG) yb[(quad*4 + r)*GG + c16] = y;
    }

    // w3 = y @ Ww2 + bw2 ; lane covers s=c16, g' in {quad, quad+4, quad+8}
    float w3[3];
    #pragma unroll
    for (int gi = 0; gi < 3; ++gi) {
        const int gpp = quad + gi*4;
        float a2 = sbw2[gpp];
        #pragma unroll
        for (int gg2 = 0; gg2 < GG; ++gg2)
            a2 += yb[c16*GG + gg2] * sWw2[gg2*GG + gpp];
        w3[gi] = a2;
    }

    // softmax over s (c16-lanes), then * mask — all DPP
    #pragma unroll
    for (int gi = 0; gi < 3; ++gi) {
        const float mx = row16_max(w3[gi]);
        const float e  = __expf(w3[gi] - mx);
        const float tot = row16_sum(e);
        w3[gi] = e / tot * m;
    }
    #pragma unroll
    for (int gi = 0; gi < 3; ++gi)
        sw[c16*GG + quad + 4*gi] = w3[gi];   // safe: all yb reads above are done

    // ---- merged epilogue: out[col] = sum_s (m_s*val[s][col] + peb[s][col]) * w[s][g]
    // peb via deferred MFMAs (frags straight from global/L2, coalesced 1 KB/wave)
    #pragma unroll
    for (int ntp = 0; ntp < 3; ++ntp) {
        const int nt0 = 2*ntp, nt1 = 2*ntp + 1;
        float va[2][4];
        #pragma unroll
        for (int h = 0; h < 2; ++h)
            #pragma unroll
            for (int r = 0; r < 4; ++r)
                va[h][r] = valw[(size_t)sid[r]*CC + (2*ntp + h)*16 + c16];

        f32x4 pa = zero4, pb = zero4;
        #pragma unroll
        for (int kb = 0; kb < 3; ++kb) {
            const bf16x8 bfa = *(const bf16x8*)(fragP2 + ((nt0*3 + kb)*64 + lane)*8);
            const bf16x8 bfb = *(const bf16x8*)(fragP2 + ((nt1*3 + kb)*64 + lane)*8);
            pa = __builtin_amdgcn_mfma_f32_16x16x32_bf16(t1A[kb], bfa, pa, 0, 0, 0);
            pb = __builtin_amdgcn_mfma_f32_16x16x32_bf16(t1A[kb], bfb, pb, 0, 0, 0);
        }
        #pragma unroll
        for (int h = 0; h < 2; ++h) {
            const int nt = 2*ntp + h;
            const f32x4& pc = (h == 0) ? pa : pb;
            const float b2   = sbp2[nt*16 + c16];
            const int   gidx = 2*nt + (c16 >> 3);
            float a2 = 0.f;
            #pragma unroll
            for (int r = 0; r < 4; ++r)
                a2 += (pc[r] + b2 + mr[r]*va[h][r]) * sw[(quad*4 + r)*GG + gidx];
            a2 += __shfl_xor(a2, 16, 64);
            a2 += __shfl_xor(a2, 32, 64);
            if (quad == 0) out[(size_t)n*CC + nt*16 + c16] = a2;
        }
    }
}

extern "C" void kernel_launch(void* const* d_in, const int* in_sizes, int n_in,
                              void* d_out, int out_size, void* d_ws, size_t ws_size,
                              hipStream_t stream)
{
    const float* q     = (const float*)d_in[0];
    const float* k     = (const float*)d_in[1];
    const float* v     = (const float*)d_in[2];
    const float* xyz   = (const float*)d_in[3];
    const int*   ridx  = (const int*)d_in[4];
    const float* Wq    = (const float*)d_in[5];
    const float* bq    = (const float*)d_in[6];
    const float* gq    = (const float*)d_in[7];
    const float* betaq = (const float*)d_in[8];
    const float* Wk    = (const float*)d_in[9];
    const float* bk    = (const float*)d_in[10];
    const float* gk    = (const float*)d_in[11];
    const float* betak = (const float*)d_in[12];
    const float* Wv    = (const float*)d_in[13];
    const float* bv    = (const float*)d_in[14];
    const float* Wp1   = (const float*)d_in[15];
    const float* bp1   = (const float*)d_in[16];
    const float* gp    = (const float*)d_in[17];
    const float* betap = (const float*)d_in[18];
    const float* Wp2   = (const float*)d_in[19];
    const float* bp2   = (const float*)d_in[20];
    const float* Ww1   = (const float*)d_in[21];
    const float* bw1   = (const float*)d_in[22];
    const float* gw    = (const float*)d_in[23];
    const float* betaw = (const float*)d_in[24];
    const float* Ww2   = (const float*)d_in[25];
    const float* bw2   = (const float*)d_in[26];
    float* out = (float*)d_out;

    float* ws = (float*)d_ws;
    float* valw   = ws;                                  // [N, 96]
    float* kw1w   = valw + (size_t)NN*CC;                // [N, 12]
    float* qw1w   = kw1w + (size_t)NN*GG;                // [N, 12]
    float* cfused = qw1w + (size_t)NN*GG;                // 16
    float* statsp = cfused + 16;                         // 20 (+pad 4)
    ushort* fragQKV = (ushort*)(statsp + 24);            // 3*9216
    ushort* fragP2  = fragQKV + 3*9216;                  // 9216
    ushort* fragW1  = fragP2 + 9216;                     // 1536
    ushort* fragWf  = fragW1 + 1536;                     // 1536

    prep_kernel<<<dim3(157, 1, 1), 256, 0, stream>>>(
        Wq, Wk, Wv, Wp2, Ww1, bp2, bw1, Wp1, bp1,
        fragQKV, fragP2, fragW1, fragWf, cfused, statsp);

    qkv_mfma<<<dim3(625, 3, 1), 256, 0, stream>>>(
        q, k, v, bq, gq, betaq, bk, gk, betak, bv,
        fragQKV, fragW1, valw, qw1w, kw1w);

    attn2<<<dim3(10000, 1, 1), 256, 0, stream>>>(
        xyz, ridx, gp, betap, Wp1, bp1, bp2,
        gw, betaw, Ww2, bw2, cfused, statsp,
        fragP2, fragWf, valw, kw1w, qw1w, out);
}

// Round 11
// 217.854 us; speedup vs baseline: 1.0754x; 1.0754x over previous
//
#include <hip/hip_runtime.h>

#define NN 40000
#define SS 16
#define CC 96
#define GG 12
#define SXP 104   // ushort stride for qkv transpose buffer: 208 B rows, 16B-aligned frag reads

typedef __attribute__((ext_vector_type(8))) short bf16x8;
typedef __attribute__((ext_vector_type(4))) float f32x4;

// float -> bf16 (RNE), raw 16-bit pattern (prep-path quality)
__device__ __forceinline__ short f2bf(float f) {
    union { float f; unsigned u; } c; c.f = f;
    unsigned r = (c.u + 0x7fffu + ((c.u >> 16) & 1u)) >> 16;
    return (short)r;
}
// pack two floats -> (bf16(hi)<<16)|bf16(lo) in ONE v_perm_b32 (+half-up rounding)
__device__ __forceinline__ unsigned pack2bf(float hi, float lo) {
    unsigned a = __float_as_uint(hi) + 0x8000u;
    unsigned b = __float_as_uint(lo) + 0x8000u;
    return __builtin_amdgcn_perm(a, b, 0x07060302u);
}
// single float -> bf16 (half-up, 2 ops)
__device__ __forceinline__ ushort f2bf_hu(float f) {
    return (ushort)((__float_as_uint(f) + 0x8000u) >> 16);
}

// ---- DPP cross-lane within 16-lane rows (~2 cyc vs ~120 for ds_bpermute) ----
template<int CTRL>
__device__ __forceinline__ float dppf(float x) {
    int r = __builtin_amdgcn_mov_dpp(__float_as_int(x), CTRL, 0xF, 0xF, true);
    return __int_as_float(r);
}
__device__ __forceinline__ float row16_sum(float x) {
    x += dppf<0xB1>(x);    // quad_perm [1,0,3,2]
    x += dppf<0x4E>(x);    // quad_perm [2,3,0,1]
    x += dppf<0x141>(x);   // ROW_HALF_MIRROR
    x += dppf<0x140>(x);   // ROW_MIRROR
    return x;
}
__device__ __forceinline__ float row16_max(float x) {
    x = fmaxf(x, dppf<0xB1>(x));
    x = fmaxf(x, dppf<0x4E>(x));
    x = fmaxf(x, dppf<0x141>(x));
    x = fmaxf(x, dppf<0x140>(x));
    return x;
}

// job-range constants for prep
#define J_W3   27648            // 3 x 9216: Wq/Wk/Wv frags
#define J_P2   (J_W3 + 9216)    // Wp2 frags
#define J_W1   (J_P2 + 1536)    // Ww1 frags (padded to 16 cols)
#define J_WF   (J_W1 + 1536)    // Wfused frags (direct 96-dot)
#define J_CF   (J_WF + 12)      // cfused
#define J_S4   (J_CF + 4)       // s4 = A^T 1
#define J_G    (J_S4 + 16)      // G = A^T A
// grid = ceil(J_G/256) = 157

// ---------------- prep: all weight fragments + LN-stats, once ----------------
__global__ void prep_kernel(const float* __restrict__ Wq, const float* __restrict__ Wk,
                            const float* __restrict__ Wv, const float* __restrict__ Wp2,
                            const float* __restrict__ Ww1, const float* __restrict__ bp2,
                            const float* __restrict__ bw1, const float* __restrict__ Wp1,
                            const float* __restrict__ bp1,
                            ushort* __restrict__ fragQKV, ushort* __restrict__ fragP2,
                            ushort* __restrict__ fragW1, ushort* __restrict__ fragWf,
                            float* __restrict__ cfused, float* __restrict__ stats)
{
    const int job = blockIdx.x*256 + threadIdx.x;
    if (job < J_W3) {
        const int which = job / 9216, o = job % 9216;
        const float* W = (which == 0) ? Wq : (which == 1) ? Wk : Wv;
        const int pos = o >> 3, j = o & 7;
        const int lane = pos & 63, ntkb = pos >> 6;
        const int nt = ntkb / 3, kb = ntkb - nt*3;
        const int col = nt*16 + (lane & 15), krow = kb*32 + (lane >> 4)*8 + j;
        fragQKV[job] = (ushort)f2bf(W[krow*CC + col]);
    } else if (job < J_P2) {
        const int o = job - J_W3;
        const int pos = o >> 3, j = o & 7;
        const int lane = pos & 63, ntkb = pos >> 6;
        const int nt = ntkb / 3, kb = ntkb - nt*3;
        const int col = nt*16 + (lane & 15), krow = kb*32 + (lane >> 4)*8 + j;
        fragP2[o] = (ushort)f2bf(Wp2[krow*CC + col]);
    } else if (job < J_W1) {
        const int o = job - J_P2;
        const int pos = o >> 3, j = o & 7;
        const int lane = pos & 63, kb = pos >> 6;
        const int col = lane & 15, krow = kb*32 + (lane >> 4)*8 + j;
        fragW1[o] = (col < GG) ? (ushort)f2bf(Ww1[krow*GG + col]) : (ushort)0;
    } else if (job < J_WF) {
        const int o = job - J_W1;
        const int pos = o >> 3, j = o & 7;
        const int lane = pos & 63, kb = pos >> 6;
        const int col = lane & 15, krow = kb*32 + (lane >> 4)*8 + j;
        float s = 0.f;
        if (col < GG) for (int jj = 0; jj < CC; ++jj) s += Wp2[krow*CC + jj] * Ww1[jj*GG + col];
        fragWf[o] = (col < GG) ? (ushort)f2bf(s) : (ushort)0;
    } else if (job < J_CF) {
        const int g = job - J_WF;
        float s = bw1[g];
        for (int jj = 0; jj < CC; ++jj) s += bp2[jj] * Ww1[jj*GG + g];
        cfused[g] = s;
    } else if (job < J_S4) {
        const int d = job - J_CF;
        float s = 0.f;
        for (int c = 0; c < CC; ++c) s += (d < 3) ? Wp1[d*CC + c] : bp1[c];
        stats[d] = s;
    } else if (job < J_G) {
        const int o = job - J_S4, d1 = o >> 2, d2 = o & 3;
        float s = 0.f;
        for (int c = 0; c < CC; ++c) {
            const float a1 = (d1 < 3) ? Wp1[d1*CC + c] : bp1[c];
            const float a2 = (d2 < 3) ? Wp1[d2*CC + c] : bp1[c];
            s += a1*a2;
        }
        stats[4 + o] = s;
    }
}

// ---------------- Kernel A: q/k/v projections via MFMA, ONE tile per wave ----------------
// One-shot B-frag reads from global (each frag used once per wave -> LDS staging
// buys nothing; R10 residual confirmed neutral). bf16 transpose buffer (stride 104
// ush: 16B-aligned frag reads, 2-way bank aliasing = free). LDS ~14.5 KB.
__global__ __launch_bounds__(256) void qkv_mfma(
    const float* __restrict__ q, const float* __restrict__ kx, const float* __restrict__ v,
    const float* __restrict__ bq, const float* __restrict__ gq, const float* __restrict__ betaq,
    const float* __restrict__ bk, const float* __restrict__ gk, const float* __restrict__ betak,
    const float* __restrict__ bv,
    const ushort* __restrict__ fragQKV, const ushort* __restrict__ fragW1,
    float* __restrict__ valout, float* __restrict__ qw1out, float* __restrict__ kw1out)
{
    __shared__ float sbias[CC], sg[CC], sbeta[CC];
    __shared__ __align__(16) ushort sx2[4][16*SXP];   // per-wave bf16 transpose buffer

    const int p = blockIdx.y;
    const float* X; const float* b;
    const float* g = nullptr; const float* beta = nullptr;
    if (p == 0)      { X = q;  b = bq; g = gq; beta = betaq; }
    else if (p == 1) { X = kx; b = bk; g = gk; beta = betak; }
    else             { X = v;  b = bv; }
    const bool has_ln = (p < 2);
    float* w1out = (p == 0) ? qw1out : kw1out;

    const int t = threadIdx.x;
    if (t < CC) {
        sbias[t] = b[t];
        if (has_ln) { sg[t] = g[t]; sbeta[t] = beta[t]; }
    }

    const int lane = t & 63, w = t >> 6;
    const int c16 = lane & 15, quad = lane >> 4;
    const ushort* fragW = fragQKV + p*9216;

    bf16x8 Ww1f[3];
    if (has_ln) {
        #pragma unroll
        for (int kb = 0; kb < 3; ++kb) {
            union { bf16x8 v; uint4 u; } wu;
            wu.u = ((const uint4*)fragW1)[kb*64 + lane];
            Ww1f[kb] = wu.v;
        }
    }

    __syncthreads();

    const f32x4 zero4 = {0.f, 0.f, 0.f, 0.f};
    ushort* sxw = sx2[w];
    const int tile = blockIdx.x*4 + w;     // exactly 2500 tiles
    const int row0 = tile * 16;

    const float* xr = X + (size_t)(row0 + c16)*CC;
    bf16x8 Af[3];
    #pragma unroll
    for (int kb = 0; kb < 3; ++kb) {
        const float4 a0 = *(const float4*)(xr + kb*32 + quad*8);
        const float4 a1 = *(const float4*)(xr + kb*32 + quad*8 + 4);
        union { bf16x8 v; uint u[4]; } au;
        au.u[0] = pack2bf(a0.y, a0.x);
        au.u[1] = pack2bf(a0.w, a0.z);
        au.u[2] = pack2bf(a1.y, a1.x);
        au.u[3] = pack2bf(a1.w, a1.z);
        Af[kb] = au.v;
    }

    f32x4 acc[6];
    #pragma unroll
    for (int nt = 0; nt < 6; ++nt) acc[nt] = zero4;
    #pragma unroll
    for (int kb = 0; kb < 3; ++kb)
        #pragma unroll
        for (int nt = 0; nt < 6; ++nt) {
            const bf16x8 bf = *(const bf16x8*)(fragW + ((nt*3 + kb)*64 + lane)*8);
            acc[nt] = __builtin_amdgcn_mfma_f32_16x16x32_bf16(Af[kb], bf, acc[nt], 0, 0, 0);
        }

    #pragma unroll
    for (int nt = 0; nt < 6; ++nt) {
        const float bb = sbias[nt*16 + c16];
        #pragma unroll
        for (int r = 0; r < 4; ++r) acc[nt][r] += bb;
    }

    if (has_ln) {
        #pragma unroll
        for (int r = 0; r < 4; ++r) {
            float sum = 0.f, sq = 0.f;
            #pragma unroll
            for (int nt = 0; nt < 6; ++nt) { float x = acc[nt][r]; sum += x; sq += x*x; }
            sum = row16_sum(sum); sq = row16_sum(sq);
            const float mu  = sum * (1.f/96.f);
            const float var = sq * (1.f/96.f) - mu*mu;
            const float rs  = rsqrtf(var + 1e-5f);
            #pragma unroll
            for (int nt = 0; nt < 6; ++nt) {
                const int c = nt*16 + c16;
                acc[nt][r] = fmaxf((acc[nt][r] - mu)*rs*sg[c] + sbeta[c], 0.f);
            }
        }
        // C/D -> per-wave bf16 LDS -> direct A-frag readback (no repacking)
        #pragma unroll
        for (int nt = 0; nt < 6; ++nt)
            #pragma unroll
            for (int r = 0; r < 4; ++r)
                sxw[(quad*4 + r)*SXP + nt*16 + c16] = f2bf_hu(acc[nt][r]);

        f32x4 o = zero4;
        #pragma unroll
        for (int kb = 0; kb < 3; ++kb) {
            const bf16x8 aA = *(const bf16x8*)(sxw + c16*SXP + kb*32 + quad*8);
            o = __builtin_amdgcn_mfma_f32_16x16x32_bf16(aA, Ww1f[kb], o, 0, 0, 0);
        }
        if (c16 < GG) {
            #pragma unroll
            for (int r = 0; r < 4; ++r)
                w1out[(size_t)(row0 + quad*4 + r)*GG + c16] = o[r];
        }
    } else {
        #pragma unroll
        for (int r = 0; r < 4; ++r)
            #pragma unroll
            for (int nt = 0; nt < 6; ++nt)
                valout[(size_t)(row0 + quad*4 + r)*CC + nt*16 + c16] = acc[nt][r];
    }
}

// ---------------- Kernel B: grouped vector attention, ONE node per wave ----------------
// grid 10000. Wp2 B-frags STAY IN LDS (R10: reading them from global/L2 inside the
// per-node epilogue regressed 81->93 µs — L2 latency feeds MFMAs serially). Wfused
// frags in 12 VGPRs (one-time load). yb/sw aliased. LDS ~25 KB -> 6 blocks/CU.
// NEVER force min-occupancy (R4/R6 spills).
__global__ __launch_bounds__(256) void attn2(
    const float* __restrict__ xyz, const int* __restrict__ refidx,
    const float* __restrict__ gp,  const float* __restrict__ betap,
    const float* __restrict__ Wp1, const float* __restrict__ bp1,
    const float* __restrict__ bp2,
    const float* __restrict__ gw,  const float* __restrict__ betaw,
    const float* __restrict__ Ww2, const float* __restrict__ bw2,
    const float* __restrict__ cfused, const float* __restrict__ stats,
    const ushort* __restrict__ fragP2, const ushort* __restrict__ fragWf,
    const float* __restrict__ valw, const float* __restrict__ kw1w, const float* __restrict__ qw1w,
    float* __restrict__ out)
{
    __shared__ __align__(16) ushort sWp2f[9216];   // Wp2 B-frags, 18 KB
    __shared__ float4 sA[CC];                      // (Wp1 row0, row1, row2, bp1) per col
    __shared__ float2 sGB[CC];                     // (gp, betap) per col
    __shared__ float  sbp2[CC];
    __shared__ float  sWw2[GG*GG];
    __shared__ float  sgw[16], sbetaw[16], sbw2[16], scf[16];
    __shared__ float  sstats[20];
    __shared__ float  ybuf[4][SS*GG];              // yb then sw (aliased, wave-local)

    const int t = threadIdx.x;
    if (t < CC) {
        sA[t]  = make_float4(Wp1[t], Wp1[CC + t], Wp1[2*CC + t], bp1[t]);
        sGB[t] = make_float2(gp[t], betap[t]);
        sbp2[t] = bp2[t];
    }
    if (t < GG*GG) sWw2[t] = Ww2[t];
    if (t < 16) {
        sgw[t]    = (t < GG) ? gw[t]     : 0.f;
        sbetaw[t] = (t < GG) ? betaw[t]  : 0.f;
        sbw2[t]   = (t < GG) ? bw2[t]    : 0.f;
        scf[t]    = (t < GG) ? cfused[t] : 0.f;
    }
    if (t < 20) sstats[t] = stats[t];
    for (int i = t; i < 1152; i += 256) ((uint4*)sWp2f)[i] = ((const uint4*)fragP2)[i];

    const int lane = t & 63, w = t >> 6;
    const int c16 = lane & 15, quad = lane >> 4;
    const int gcl = (c16 < GG) ? c16 : (GG-1);

    // Wfused B-frags in registers (one-time coalesced load)
    bf16x8 Wff[3];
    #pragma unroll
    for (int kb = 0; kb < 3; ++kb) {
        union { bf16x8 v; uint4 u; } wu;
        wu.u = ((const uint4*)fragWf)[kb*64 + lane];
        Wff[kb] = wu.v;
    }

    __syncthreads();   // staging done; below is wave-synchronous

    float* yb = ybuf[w];
    float* sw = ybuf[w];   // aliased: all yb reads complete before sw writes
    const f32x4 zero4 = {0.f, 0.f, 0.f, 0.f};

    const int n = blockIdx.x*4 + w;   // one node per wave

    // ---- per-lane neighbor (s = c16) for t1 ----
    const int   id   = refidx[(size_t)n*SS + c16];
    const float m    = (id >= 0) ? 1.f : 0.f;
    const int   safe = (id < 0) ? 0 : id;

    // ---- C/D-layout row indices (s = quad*4+r), loaded EARLY so the kw1
    // gather latency overlaps t1 compute
    int sid[4]; float mr[4], kwv[4];
    #pragma unroll
    for (int r = 0; r < 4; ++r) {
        const int sd = refidx[(size_t)n*SS + quad*4 + r];
        mr[r]  = (sd >= 0) ? 1.f : 0.f;
        sid[r] = (sd < 0) ? 0 : sd;
    }
    #pragma unroll
    for (int r = 0; r < 4; ++r)
        kwv[r] = kw1w[(size_t)sid[r]*GG + gcl] * mr[r];
    const float qv = qw1w[(size_t)n*GG + gcl];

    const float px = (xyz[(size_t)safe*3 + 0] - xyz[(size_t)n*3 + 0]) * m;
    const float py = (xyz[(size_t)safe*3 + 1] - xyz[(size_t)n*3 + 1]) * m;
    const float pz = (xyz[(size_t)safe*3 + 2] - xyz[(size_t)n*3 + 2]) * m;

    // ---- LN stats of (pos@Wp1+bp1) from precomputed s4/G: no reduction ----
    const float mu = (px*sstats[0] + py*sstats[1] + pz*sstats[2] + sstats[3]) * (1.f/96.f);
    float e2 = 0.f;
    {
        const float p4[4] = {px, py, pz, 1.f};
        #pragma unroll
        for (int a = 0; a < 4; ++a) {
            float ta = 0.f;
            #pragma unroll
            for (int b2 = 0; b2 < 4; ++b2) ta = fmaf(sstats[4 + a*4 + b2], p4[b2], ta);
            e2 = fmaf(p4[a], ta, e2);
        }
    }
    const float var = e2*(1.f/96.f) - mu*mu;
    const float rs  = rsqrtf(var + 1e-5f);

    // ---- t1 = relu(ln(..)) directly into A-frag bf16 (perm-packed) ----
    bf16x8 t1A[3];
    #pragma unroll
    for (int kb = 0; kb < 3; ++kb) {
        union { bf16x8 v; uint u[4]; } tu;
        #pragma unroll
        for (int jp = 0; jp < 4; ++jp) {
            float tt[2];
            #pragma unroll
            for (int h = 0; h < 2; ++h) {
                const int c = kb*32 + quad*8 + jp*2 + h;
                const float4 aw = sA[c];
                const float x = fmaf(px, aw.x, fmaf(py, aw.y, fmaf(pz, aw.z, aw.w)));
                const float2 gb = sGB[c];
                tt[h] = fmaxf(fmaf((x - mu)*rs, gb.x, gb.y), 0.f);
            }
            tu.u[jp] = pack2bf(tt[1], tt[0]);
        }
        t1A[kb] = tu.v;
    }

    // ---- t2 = t1 @ Wfused (frags in regs) ----
    f32x4 t2 = zero4;
    #pragma unroll
    for (int kb = 0; kb < 3; ++kb)
        t2 = __builtin_amdgcn_mfma_f32_16x16x32_bf16(t1A[kb], Wff[kb], t2, 0, 0, 0);
    #pragma unroll
    for (int r = 0; r < 4; ++r)
        t2[r] += kwv[r] - qv + scf[c16];

    // LN over G=12 (rows s=quad*4+r, lane col g=c16) via DPP
    #pragma unroll
    for (int r = 0; r < 4; ++r) {
        const float x = (c16 < GG) ? t2[r] : 0.f;
        const float s1 = row16_sum(x);
        const float s2 = row16_sum(x*x);
        const float mu2  = s1 * (1.f/12.f);
        const float var2 = s2 * (1.f/12.f) - mu2*mu2;
        const float rs2  = rsqrtf(var2 + 1e-5f);
        const float y    = fmaxf((t2[r] - mu2)*rs2*sgw[c16] + sbetaw[c16], 0.f);
        if (c16 < GG) yb[(quad*4 + r)*GG + c16] = y;
    }

    // w3 = y @ Ww2 + bw2 ; lane covers s=c16, g' in {quad, quad+4, quad+8}
    float w3[3];
    #pragma unroll
    for (int gi = 0; gi < 3; ++gi) {
        const int gpp = quad + gi*4;
        float a2 = sbw2[gpp];
        #pragma unroll
        for (int gg2 = 0; gg2 < GG; ++gg2)
            a2 += yb[c16*GG + gg2] * sWw2[gg2*GG + gpp];
        w3[gi] = a2;
    }

    // softmax over s (c16-lanes), then * mask — all DPP
    #pragma unroll
    for (int gi = 0; gi < 3; ++gi) {
        const float mx = row16_max(w3[gi]);
        const float e  = __expf(w3[gi] - mx);
        const float tot = row16_sum(e);
        w3[gi] = e / tot * m;
    }
    #pragma unroll
    for (int gi = 0; gi < 3; ++gi)
        sw[c16*GG + quad + 4*gi] = w3[gi];   // safe: all yb reads above are done

    // ---- merged epilogue: out[col] = sum_s (m_s*val[s][col] + peb[s][col]) * w[s][g]
    // peb via deferred MFMAs, B-frags from LDS (ds_read_b128)
    #pragma unroll
    for (int ntp = 0; ntp < 3; ++ntp) {
        const int nt0 = 2*ntp, nt1 = 2*ntp + 1;
        float va[2][4];
        #pragma unroll
        for (int h = 0; h < 2; ++h)
            #pragma unroll
            for (int r = 0; r < 4; ++r)
                va[h][r] = valw[(size_t)sid[r]*CC + (2*ntp + h)*16 + c16];

        f32x4 pa = zero4, pb = zero4;
        #pragma unroll
        for (int kb = 0; kb < 3; ++kb) {
            const bf16x8 bfa = *(const bf16x8*)(sWp2f + ((nt0*3 + kb)*64 + lane)*8);
            const bf16x8 bfb = *(const bf16x8*)(sWp2f + ((nt1*3 + kb)*64 + lane)*8);
            pa = __builtin_amdgcn_mfma_f32_16x16x32_bf16(t1A[kb], bfa, pa, 0, 0, 0);
            pb = __builtin_amdgcn_mfma_f32_16x16x32_bf16(t1A[kb], bfb, pb, 0, 0, 0);
        }
        #pragma unroll
        for (int h = 0; h < 2; ++h) {
            const int nt = 2*ntp + h;
            const f32x4& pc = (h == 0) ? pa : pb;
            const float b2   = sbp2[nt*16 + c16];
            const int   gidx = 2*nt + (c16 >> 3);
            float a2 = 0.f;
            #pragma unroll
            for (int r = 0; r < 4; ++r)
                a2 += (pc[r] + b2 + mr[r]*va[h][r]) * sw[(quad*4 + r)*GG + gidx];
            a2 += __shfl_xor(a2, 16, 64);
            a2 += __shfl_xor(a2, 32, 64);
            if (quad == 0) out[(size_t)n*CC + nt*16 + c16] = a2;
        }
    }
}

extern "C" void kernel_launch(void* const* d_in, const int* in_sizes, int n_in,
                              void* d_out, int out_size, void* d_ws, size_t ws_size,
                              hipStream_t stream)
{
    const float* q     = (const float*)d_in[0];
    const float* k     = (const float*)d_in[1];
    const float* v     = (const float*)d_in[2];
    const float* xyz   = (const float*)d_in[3];
    const int*   ridx  = (const int*)d_in[4];
    const float* Wq    = (const float*)d_in[5];
    const float* bq    = (const float*)d_in[6];
    const float* gq    = (const float*)d_in[7];
    const float* betaq = (const float*)d_in[8];
    const float* Wk    = (const float*)d_in[9];
    const float* bk    = (const float*)d_in[10];
    const float* gk    = (const float*)d_in[11];
    const float* betak = (const float*)d_in[12];
    const float* Wv    = (const float*)d_in[13];
    const float* bv    = (const float*)d_in[14];
    const float* Wp1   = (const float*)d_in[15];
    const float* bp1   = (const float*)d_in[16];
    const float* gp    = (const float*)d_in[17];
    const float* betap = (const float*)d_in[18];
    const float* Wp2   = (const float*)d_in[19];
    const float* bp2   = (const float*)d_in[20];
    const float* Ww1   = (const float*)d_in[21];
    const float* bw1   = (const float*)d_in[22];
    const float* gw    = (const float*)d_in[23];
    const float* betaw = (const float*)d_in[24];
    const float* Ww2   = (const float*)d_in[25];
    const float* bw2   = (const float*)d_in[26];
    float* out = (float*)d_out;

    float* ws = (float*)d_ws;
    float* valw   = ws;                                  // [N, 96]
    float* kw1w   = valw + (size_t)NN*CC;                // [N, 12]
    float* qw1w   = kw1w + (size_t)NN*GG;                // [N, 12]
    float* cfused = qw1w + (size_t)NN*GG;                // 16
    float* statsp = cfused + 16;                         // 20 (+pad 4)
    ushort* fragQKV = (ushort*)(statsp + 24);            // 3*9216
    ushort* fragP2  = fragQKV + 3*9216;                  // 9216
    ushort* fragW1  = fragP2 + 9216;                     // 1536
    ushort* fragWf  = fragW1 + 1536;                     // 1536

    prep_kernel<<<dim3(157, 1, 1), 256, 0, stream>>>(
        Wq, Wk, Wv, Wp2, Ww1, bp2, bw1, Wp1, bp1,
        fragQKV, fragP2, fragW1, fragWf, cfused, statsp);

    qkv_mfma<<<dim3(625, 3, 1), 256, 0, stream>>>(
        q, k, v, bq, gq, betaq, bk, gk, betak, bv,
        fragQKV, fragW1, valw, qw1w, kw1w);

    attn2<<<dim3(10000, 1, 1), 256, 0, stream>>>(
        xyz, ridx, gp, betap, Wp1, bp1, bp2,
        gw, betaw, Ww2, bw2, cfused, statsp,
        fragP2, fragWf, valw, kw1w, qw1w, out);
}